// Round 7
// baseline (366.676 us; speedup 1.0000x reference)
//
#include <hip/hip_runtime.h>

constexpr int N_NODES = 100000;
constexpr int N_EDGES = 1600000;
constexpr int NPART = 8;
constexpr int PART_SZ = (N_NODES + NPART - 1) / NPART;   // 12500
constexpr int CAP = 64;   // bucket capacity; degree ~Poisson(16), P(deg>=64)~1e-19

typedef short short8 __attribute__((ext_vector_type(8)));
typedef float f32x4 __attribute__((ext_vector_type(4)));

__device__ __forceinline__ unsigned short f2bf(float f) {
    unsigned int u = __float_as_uint(f);
    unsigned int r = (u + 0x7fff + ((u >> 16) & 1)) >> 16;   // RTN-even
    return (unsigned short)r;
}
__device__ __forceinline__ float bflo(unsigned int u) { return __uint_as_float(u << 16); }
__device__ __forceinline__ float bfhi(unsigned int u) { return __uint_as_float(u & 0xffff0000u); }

// A-matrix row layout: [0..127] = aggr (k<128, W_rel), [128..255] = h (k>=128, W_root)

// ---------------- weight packing: B-fragment order, bf16 ----------------
__global__ __launch_bounds__(256) void pack_w(const float* __restrict__ wrel,
                                              const float* __restrict__ wroot,
                                              unsigned short* __restrict__ packed) {
    int t = blockIdx.x * 256 + threadIdx.x;   // 0..32767
    int j = t & 7, lane = (t >> 3) & 63, ks = (t >> 9) & 7, nt = (t >> 12) & 7;
    int k = ks * 32 + ((lane >> 4) << 3) + j;
    int n = nt * 16 + (lane & 15);
    float v = (k < 128) ? wrel[n * 128 + k] : wroot[n * 128 + (k - 128)];
    packed[t] = f2bf(v);
}

// x fp32 -> h-part bf16 of A
__global__ __launch_bounds__(256) void convert_x(const float* __restrict__ x,
                                                 unsigned short* __restrict__ A) {
    int i = blockIdx.x * 256 + threadIdx.x;
    if (i >= N_NODES * 64) return;
    int node = i >> 6, c2 = (i & 63) * 2;
    float2 v = *(const float2*)&x[(size_t)node * 128 + c2];
    unsigned int out = (unsigned int)f2bf(v.x) | ((unsigned int)f2bf(v.y) << 16);
    *(unsigned int*)&A[(size_t)node * 256 + 128 + c2] = out;
}

// ---------------- single-pass bucket CSR (XCD-partitioned by dst range) ----
// Nontemporal streaming reads: don't evict the partition's cnt/bkt lines from
// the XCD's L2 (they must stay resident until fully populated to avoid
// partial-line writeback amplification — R6 showed 8x: WRITE 79MB vs 10MB).
__global__ __launch_bounds__(256) void bucket_fill_part(const int* __restrict__ src,
                                                        const int* __restrict__ dst,
                                                        int* __restrict__ cnt,
                                                        int* __restrict__ bkt) {
    int p = blockIdx.x & 7;
    int nb = gridDim.x >> 3;
    int bi = blockIdx.x >> 3;
    int lo = p * PART_SZ, hi = lo + PART_SZ;
    for (int e = bi * 256 + threadIdx.x; e < N_EDGES; e += nb * 256) {
        int d = __builtin_nontemporal_load(dst + e);
        if (d >= lo && d < hi) {
            int s = __builtin_nontemporal_load(src + e);
            int pos = atomicAdd(&cnt[d], 1);
            bkt[(d << 6) + pos] = s;
        }
    }
}

// ---------------- per-layer kernels ----------------
// One 64-lane wave per node, in-place on A: reads h-part (offset 128) of
// neighbor rows, writes aggr-part (offset 0) of own row. lane>>4 = edge slot
// (4 rows in flight), lane&15 = 16B chunk; 2x unrolled -> 8 rows in flight.
__global__ __launch_bounds__(256) void gather_bucket(const int* __restrict__ cnt_arr,
                                                     const int* __restrict__ bkt,
                                                     unsigned short* __restrict__ A) {
    int wid = (blockIdx.x * 256 + threadIdx.x) >> 6;
    int lane = threadIdx.x & 63;
    if (wid >= N_NODES) return;
    int cnt = cnt_arr[wid];
    cnt = (cnt > CAP) ? CAP : cnt;
    const int* bp = bkt + (wid << 6);
    int g = lane >> 4;
    int ch = lane & 15;
    float acc[8] = {};
    int e = 0;
    for (; e + 8 <= cnt; e += 8) {
        int s0 = bp[e + g];
        int s1 = bp[e + 4 + g];
        uint4 u0 = *(const uint4*)&A[(size_t)s0 * 256 + 128 + ch * 8];
        uint4 u1 = *(const uint4*)&A[(size_t)s1 * 256 + 128 + ch * 8];
        acc[0] += bflo(u0.x); acc[1] += bfhi(u0.x);
        acc[2] += bflo(u0.y); acc[3] += bfhi(u0.y);
        acc[4] += bflo(u0.z); acc[5] += bfhi(u0.z);
        acc[6] += bflo(u0.w); acc[7] += bfhi(u0.w);
        acc[0] += bflo(u1.x); acc[1] += bfhi(u1.x);
        acc[2] += bflo(u1.y); acc[3] += bfhi(u1.y);
        acc[4] += bflo(u1.z); acc[5] += bfhi(u1.z);
        acc[6] += bflo(u1.w); acc[7] += bfhi(u1.w);
    }
    for (; e < cnt; e += 4) {
        int ei = e + g;
        if (ei < cnt) {
            int s0 = bp[ei];
            uint4 u0 = *(const uint4*)&A[(size_t)s0 * 256 + 128 + ch * 8];
            acc[0] += bflo(u0.x); acc[1] += bfhi(u0.x);
            acc[2] += bflo(u0.y); acc[3] += bfhi(u0.y);
            acc[4] += bflo(u0.z); acc[5] += bfhi(u0.z);
            acc[6] += bflo(u0.w); acc[7] += bfhi(u0.w);
        }
    }
    #pragma unroll
    for (int j = 0; j < 8; ++j) {
        acc[j] += __shfl_xor(acc[j], 16);
        acc[j] += __shfl_xor(acc[j], 32);
    }
    if (g == 0) {
        uint4 o;
        o.x = (unsigned int)f2bf(acc[0]) | ((unsigned int)f2bf(acc[1]) << 16);
        o.y = (unsigned int)f2bf(acc[2]) | ((unsigned int)f2bf(acc[3]) << 16);
        o.z = (unsigned int)f2bf(acc[4]) | ((unsigned int)f2bf(acc[5]) << 16);
        o.w = (unsigned int)f2bf(acc[6]) | ((unsigned int)f2bf(acc[7]) << 16);
        *(uint4*)&A[(size_t)wid * 256 + ch * 8] = o;
    }
}

// relu(A[N,256] x W[256,128] + b). Block = 4 waves, 256 rows.
// No LDS: B-fragments read straight from global (identical across blocks ->
// L1/L2 broadcast); LDS=0 lifts occupancy to the VGPR limit for latency hiding.
// LAST=false: write h' bf16 in-place into A's h-part.
// LAST=true : fuse output layer: out[row] = dot(relu_row, w_out) + b_out.
template <bool LAST>
__global__ __launch_bounds__(256) void mfma_transform(unsigned short* __restrict__ A,
                                                      const unsigned short* __restrict__ packedW,
                                                      const float* __restrict__ brel,
                                                      const float* __restrict__ w_out,
                                                      const float* __restrict__ b_out,
                                                      float* __restrict__ outF) {
    int wave = threadIdx.x >> 6, lane = threadIdx.x & 63;
    int l15 = lane & 15, lhi = lane >> 4;
    int brow = blockIdx.x * 256 + wave * 64;
    float bias[8], wo[8];
    #pragma unroll
    for (int nt = 0; nt < 8; ++nt) {
        bias[nt] = brel[nt * 16 + l15];
        if (LAST) wo[nt] = w_out[nt * 16 + l15];
    }
    float bout = LAST ? b_out[0] : 0.f;
    const unsigned short* wp = packedW + (size_t)lane * 8;

    for (int rtp = 0; rtp < 2; ++rtp) {
        int r0 = brow + rtp * 32;
        short8 a[2][8];
        #pragma unroll
        for (int rt = 0; rt < 2; ++rt) {
            int row = r0 + rt * 16 + l15;
            if (row >= N_NODES) row = N_NODES - 1;
            const unsigned short* ap = &A[(size_t)row * 256 + lhi * 8];
            #pragma unroll
            for (int ks = 0; ks < 8; ++ks) a[rt][ks] = *(const short8*)(ap + ks * 32);
        }
        f32x4 acc[2][8] = {};
        #pragma unroll
        for (int nt = 0; nt < 8; ++nt) {
            #pragma unroll
            for (int ks = 0; ks < 8; ++ks) {
                short8 b = *(const short8*)(wp + (size_t)(nt * 8 + ks) * 512);
                acc[0][nt] = __builtin_amdgcn_mfma_f32_16x16x32_bf16(a[0][ks], b, acc[0][nt], 0, 0, 0);
                acc[1][nt] = __builtin_amdgcn_mfma_f32_16x16x32_bf16(a[1][ks], b, acc[1][nt], 0, 0, 0);
            }
        }
        #pragma unroll
        for (int rt = 0; rt < 2; ++rt) {
            if (LAST) {
                #pragma unroll
                for (int rg = 0; rg < 4; ++rg) {
                    float p = 0.f;
                    #pragma unroll
                    for (int nt = 0; nt < 8; ++nt)
                        p += fmaxf(acc[rt][nt][rg] + bias[nt], 0.f) * wo[nt];
                    p += __shfl_xor(p, 1);
                    p += __shfl_xor(p, 2);
                    p += __shfl_xor(p, 4);
                    p += __shfl_xor(p, 8);
                    int row = r0 + rt * 16 + lhi * 4 + rg;
                    if (l15 == 0 && row < N_NODES) outF[row] = p + bout;
                }
            } else {
                #pragma unroll
                for (int nt = 0; nt < 8; ++nt) {
                    #pragma unroll
                    for (int rg = 0; rg < 4; ++rg) {
                        int row = r0 + rt * 16 + lhi * 4 + rg;
                        if (row < N_NODES) {
                            float v = fmaxf(acc[rt][nt][rg] + bias[nt], 0.f);
                            A[(size_t)row * 256 + 128 + nt * 16 + l15] = f2bf(v);
                        }
                    }
                }
            }
        }
    }
}

extern "C" void kernel_launch(void* const* d_in, const int* in_sizes, int n_in,
                              void* d_out, int out_size, void* d_ws, size_t ws_size,
                              hipStream_t stream) {
    const float* x      = (const float*)d_in[0];
    const int*   edge   = (const int*)d_in[1];
    const int*   src    = edge;
    const int*   dst    = edge + N_EDGES;
    const float* w_rel[3]  = {(const float*)d_in[2], (const float*)d_in[5], (const float*)d_in[8]};
    const float* b_rel[3]  = {(const float*)d_in[3], (const float*)d_in[6], (const float*)d_in[9]};
    const float* w_root[3] = {(const float*)d_in[4], (const float*)d_in[7], (const float*)d_in[10]};
    const float* w_out  = (const float*)d_in[11];
    const float* b_out  = (const float*)d_in[12];

    // workspace: A (51.2MB) + pW (196KB) + cnt (400KB) + bkt (25.6MB) = 77.4MB
    unsigned short* A  = (unsigned short*)d_ws;              // N*256 bf16 [aggr|h]
    unsigned short* pW = A + (size_t)N_NODES * 256;          // 3 * 32768 bf16
    int* cnt = (int*)(pW + 3 * 32768);                       // N ints
    int* bkt = cnt + N_NODES;                                // N*64 ints

    for (int i = 0; i < 3; ++i)
        pack_w<<<128, 256, 0, stream>>>(w_rel[i], w_root[i], pW + (size_t)i * 32768);
    convert_x<<<(N_NODES * 64 + 255) / 256, 256, 0, stream>>>(x, A);

    // ---- bucket CSR: one pass over edges (built once, reused by 3 layers) ----
    hipMemsetAsync(cnt, 0, N_NODES * sizeof(int), stream);
    bucket_fill_part<<<2048, 256, 0, stream>>>(src, dst, cnt, bkt);

    const int gblocks = (N_NODES * 64 + 255) / 256;
    const int xblocks = (N_NODES + 255) / 256;

    // Each layer: gather h-part -> aggr-part; transform -> h-part (in place)
    gather_bucket<<<gblocks, 256, 0, stream>>>(cnt, bkt, A);
    mfma_transform<false><<<xblocks, 256, 0, stream>>>(A, pW + 0 * 32768, b_rel[0],
                                                       nullptr, nullptr, nullptr);
    gather_bucket<<<gblocks, 256, 0, stream>>>(cnt, bkt, A);
    mfma_transform<false><<<xblocks, 256, 0, stream>>>(A, pW + 1 * 32768, b_rel[1],
                                                       nullptr, nullptr, nullptr);
    gather_bucket<<<gblocks, 256, 0, stream>>>(cnt, bkt, A);
    mfma_transform<true><<<xblocks, 256, 0, stream>>>(A, pW + 2 * 32768, b_rel[2],
                                                      w_out, b_out, (float*)d_out);
}

// Round 8
// 366.118 us; speedup vs baseline: 1.0015x; 1.0015x over previous
//
#include <hip/hip_runtime.h>

constexpr int N_NODES = 100000;
constexpr int N_EDGES = 1600000;
constexpr int NPART = 8;
constexpr int PART_SZ = (N_NODES + NPART - 1) / NPART;   // 12500
constexpr int CAP = 64;     // bucket capacity; degree ~Poisson(16), P(deg>=64)~1e-19
constexpr int NBLK_A = 1024;
constexpr int EPB = (N_EDGES + NBLK_A - 1) / NBLK_A;     // 1563 edges per pass-A block
constexpr int SUBCAP = 320; // per (bin,block) capacity; expected 195, sigma 13

typedef short short8 __attribute__((ext_vector_type(8)));
typedef float f32x4 __attribute__((ext_vector_type(4)));

__device__ __forceinline__ unsigned short f2bf(float f) {
    unsigned int u = __float_as_uint(f);
    unsigned int r = (u + 0x7fff + ((u >> 16) & 1)) >> 16;   // RTN-even
    return (unsigned short)r;
}
__device__ __forceinline__ float bflo(unsigned int u) { return __uint_as_float(u << 16); }
__device__ __forceinline__ float bfhi(unsigned int u) { return __uint_as_float(u & 0xffff0000u); }

// A-matrix row layout: [0..127] = aggr (k<128, W_rel), [128..255] = h (k>=128, W_root)

// ---------------- weight packing: B-fragment order, bf16 ----------------
__global__ __launch_bounds__(256) void pack_w(const float* __restrict__ wrel,
                                              const float* __restrict__ wroot,
                                              unsigned short* __restrict__ packed) {
    int t = blockIdx.x * 256 + threadIdx.x;   // 0..32767
    int j = t & 7, lane = (t >> 3) & 63, ks = (t >> 9) & 7, nt = (t >> 12) & 7;
    int k = ks * 32 + ((lane >> 4) << 3) + j;
    int n = nt * 16 + (lane & 15);
    float v = (k < 128) ? wrel[n * 128 + k] : wroot[n * 128 + (k - 128)];
    packed[t] = f2bf(v);
}

// x fp32 -> h-part bf16 of A
__global__ __launch_bounds__(256) void convert_x(const float* __restrict__ x,
                                                 unsigned short* __restrict__ A) {
    int i = blockIdx.x * 256 + threadIdx.x;
    if (i >= N_NODES * 64) return;
    int node = i >> 6, c2 = (i & 63) * 2;
    float2 v = *(const float2*)&x[(size_t)node * 128 + c2];
    unsigned int out = (unsigned int)f2bf(v.x) | ((unsigned int)f2bf(v.y) << 16);
    *(unsigned int*)&A[(size_t)node * 256 + 128 + c2] = out;
}

// ---------------- pass A: radix-partition edges by dst range ----------------
// Block b owns edges [b*EPB, (b+1)*EPB); bins (d,s) pairs into 8 static
// sub-regions binbuf[(bin*NBLK_A + b)*SUBCAP ...]. Only LDS atomics.
__global__ __launch_bounds__(256) void partition_edges(const int* __restrict__ src,
                                                       const int* __restrict__ dst,
                                                       int2* __restrict__ binbuf,
                                                       int* __restrict__ blkcnt) {
    __shared__ int lc[8];
    if (threadIdx.x < 8) lc[threadIdx.x] = 0;
    __syncthreads();
    int base = blockIdx.x * EPB;
    for (int k = threadIdx.x; k < EPB; k += 256) {
        int e = base + k;
        if (e >= N_EDGES) break;
        int d = __builtin_nontemporal_load(dst + e);
        int s = __builtin_nontemporal_load(src + e);
        int bin = d / PART_SZ;
        int my = atomicAdd(&lc[bin], 1);
        binbuf[(size_t)(bin * NBLK_A + blockIdx.x) * SUBCAP + my] = make_int2(d, s);
    }
    __syncthreads();
    if (threadIdx.x < 8) blkcnt[blockIdx.x * 8 + threadIdx.x] = lc[threadIdx.x];
}

// ---------------- pass B: fill buckets from compact per-partition lists ----
// blockIdx&7 = partition (XCD heuristic): cnt/bkt lines for one partition
// stay in one XCD's L2; pair-list reads are nontemporal (don't evict bkt).
__global__ __launch_bounds__(256) void bucket_fill_binned(const int* __restrict__ binbuf_i,
                                                          const int* __restrict__ blkcnt,
                                                          int* __restrict__ cnt,
                                                          int* __restrict__ bkt) {
    int p = blockIdx.x & 7;
    int j = blockIdx.x >> 3;          // 0..255
    for (int i = j; i < NBLK_A; i += 256) {
        int len = blkcnt[i * 8 + p];
        const int* seg = binbuf_i + (size_t)(p * NBLK_A + i) * SUBCAP * 2;
        for (int k = threadIdx.x; k < len; k += 256) {
            int d = __builtin_nontemporal_load(seg + k * 2);
            int s = __builtin_nontemporal_load(seg + k * 2 + 1);
            int pos = atomicAdd(&cnt[d], 1);
            bkt[(d << 6) + pos] = s;
        }
    }
}

// ---------------- per-layer kernels ----------------
// One 64-lane wave per node, in-place on A: reads h-part (offset 128) of
// neighbor rows, writes aggr-part (offset 0) of own row. lane>>4 = edge slot
// (4 rows in flight), lane&15 = 16B chunk; 2x unrolled -> 8 rows in flight.
__global__ __launch_bounds__(256) void gather_bucket(const int* __restrict__ cnt_arr,
                                                     const int* __restrict__ bkt,
                                                     unsigned short* __restrict__ A) {
    int wid = (blockIdx.x * 256 + threadIdx.x) >> 6;
    int lane = threadIdx.x & 63;
    if (wid >= N_NODES) return;
    int cnt = cnt_arr[wid];
    cnt = (cnt > CAP) ? CAP : cnt;
    const int* bp = bkt + (wid << 6);
    int g = lane >> 4;
    int ch = lane & 15;
    float acc[8] = {};
    int e = 0;
    for (; e + 8 <= cnt; e += 8) {
        int s0 = bp[e + g];
        int s1 = bp[e + 4 + g];
        uint4 u0 = *(const uint4*)&A[(size_t)s0 * 256 + 128 + ch * 8];
        uint4 u1 = *(const uint4*)&A[(size_t)s1 * 256 + 128 + ch * 8];
        acc[0] += bflo(u0.x); acc[1] += bfhi(u0.x);
        acc[2] += bflo(u0.y); acc[3] += bfhi(u0.y);
        acc[4] += bflo(u0.z); acc[5] += bfhi(u0.z);
        acc[6] += bflo(u0.w); acc[7] += bfhi(u0.w);
        acc[0] += bflo(u1.x); acc[1] += bfhi(u1.x);
        acc[2] += bflo(u1.y); acc[3] += bfhi(u1.y);
        acc[4] += bflo(u1.z); acc[5] += bfhi(u1.z);
        acc[6] += bflo(u1.w); acc[7] += bfhi(u1.w);
    }
    for (; e < cnt; e += 4) {
        int ei = e + g;
        if (ei < cnt) {
            int s0 = bp[ei];
            uint4 u0 = *(const uint4*)&A[(size_t)s0 * 256 + 128 + ch * 8];
            acc[0] += bflo(u0.x); acc[1] += bfhi(u0.x);
            acc[2] += bflo(u0.y); acc[3] += bfhi(u0.y);
            acc[4] += bflo(u0.z); acc[5] += bfhi(u0.z);
            acc[6] += bflo(u0.w); acc[7] += bfhi(u0.w);
        }
    }
    #pragma unroll
    for (int j = 0; j < 8; ++j) {
        acc[j] += __shfl_xor(acc[j], 16);
        acc[j] += __shfl_xor(acc[j], 32);
    }
    if (g == 0) {
        uint4 o;
        o.x = (unsigned int)f2bf(acc[0]) | ((unsigned int)f2bf(acc[1]) << 16);
        o.y = (unsigned int)f2bf(acc[2]) | ((unsigned int)f2bf(acc[3]) << 16);
        o.z = (unsigned int)f2bf(acc[4]) | ((unsigned int)f2bf(acc[5]) << 16);
        o.w = (unsigned int)f2bf(acc[6]) | ((unsigned int)f2bf(acc[7]) << 16);
        *(uint4*)&A[(size_t)wid * 256 + ch * 8] = o;
    }
}

// relu(A[N,256] x W[256,128] + b). Block = 4 waves, 256 rows. Weights staged
// in 64KB LDS (R6-measured best). LAST=false: write h' bf16 in-place into A's
// h-part. LAST=true: fuse output layer: out[row] = dot(relu_row, w_out)+b_out.
template <bool LAST>
__global__ __launch_bounds__(256) void mfma_transform(unsigned short* __restrict__ A,
                                                      const unsigned short* __restrict__ packedW,
                                                      const float* __restrict__ brel,
                                                      const float* __restrict__ w_out,
                                                      const float* __restrict__ b_out,
                                                      float* __restrict__ outF) {
    __shared__ unsigned short sW[32768];   // 64KB
    {
        const uint4* g = (const uint4*)packedW;
        uint4* s = (uint4*)sW;
        for (int i = threadIdx.x; i < 4096; i += 256) s[i] = g[i];
    }
    __syncthreads();
    int wave = threadIdx.x >> 6, lane = threadIdx.x & 63;
    int l15 = lane & 15, lhi = lane >> 4;
    int brow = blockIdx.x * 256 + wave * 64;
    float bias[8], wo[8];
    #pragma unroll
    for (int nt = 0; nt < 8; ++nt) {
        bias[nt] = brel[nt * 16 + l15];
        if (LAST) wo[nt] = w_out[nt * 16 + l15];
    }
    float bout = LAST ? b_out[0] : 0.f;

    for (int rtp = 0; rtp < 2; ++rtp) {
        int r0 = brow + rtp * 32;
        short8 a[2][8];
        #pragma unroll
        for (int rt = 0; rt < 2; ++rt) {
            int row = r0 + rt * 16 + l15;
            if (row >= N_NODES) row = N_NODES - 1;
            const unsigned short* ap = &A[(size_t)row * 256 + lhi * 8];
            #pragma unroll
            for (int ks = 0; ks < 8; ++ks) a[rt][ks] = *(const short8*)(ap + ks * 32);
        }
        f32x4 acc[2][8] = {};
        #pragma unroll
        for (int nt = 0; nt < 8; ++nt) {
            #pragma unroll
            for (int ks = 0; ks < 8; ++ks) {
                short8 b = *(const short8*)&sW[(size_t)((nt * 8 + ks) * 64 + lane) * 8];
                acc[0][nt] = __builtin_amdgcn_mfma_f32_16x16x32_bf16(a[0][ks], b, acc[0][nt], 0, 0, 0);
                acc[1][nt] = __builtin_amdgcn_mfma_f32_16x16x32_bf16(a[1][ks], b, acc[1][nt], 0, 0, 0);
            }
        }
        #pragma unroll
        for (int rt = 0; rt < 2; ++rt) {
            if (LAST) {
                #pragma unroll
                for (int rg = 0; rg < 4; ++rg) {
                    float p = 0.f;
                    #pragma unroll
                    for (int nt = 0; nt < 8; ++nt)
                        p += fmaxf(acc[rt][nt][rg] + bias[nt], 0.f) * wo[nt];
                    p += __shfl_xor(p, 1);
                    p += __shfl_xor(p, 2);
                    p += __shfl_xor(p, 4);
                    p += __shfl_xor(p, 8);
                    int row = r0 + rt * 16 + lhi * 4 + rg;
                    if (l15 == 0 && row < N_NODES) outF[row] = p + bout;
                }
            } else {
                #pragma unroll
                for (int nt = 0; nt < 8; ++nt) {
                    #pragma unroll
                    for (int rg = 0; rg < 4; ++rg) {
                        int row = r0 + rt * 16 + lhi * 4 + rg;
                        if (row < N_NODES) {
                            float v = fmaxf(acc[rt][nt][rg] + bias[nt], 0.f);
                            A[(size_t)row * 256 + 128 + nt * 16 + l15] = f2bf(v);
                        }
                    }
                }
            }
        }
    }
}

extern "C" void kernel_launch(void* const* d_in, const int* in_sizes, int n_in,
                              void* d_out, int out_size, void* d_ws, size_t ws_size,
                              hipStream_t stream) {
    const float* x      = (const float*)d_in[0];
    const int*   edge   = (const int*)d_in[1];
    const int*   src    = edge;
    const int*   dst    = edge + N_EDGES;
    const float* w_rel[3]  = {(const float*)d_in[2], (const float*)d_in[5], (const float*)d_in[8]};
    const float* b_rel[3]  = {(const float*)d_in[3], (const float*)d_in[6], (const float*)d_in[9]};
    const float* w_root[3] = {(const float*)d_in[4], (const float*)d_in[7], (const float*)d_in[10]};
    const float* w_out  = (const float*)d_in[11];
    const float* b_out  = (const float*)d_in[12];

    // ws: A 51.2MB + pW 0.2MB + cnt 0.4MB + bkt 25.6MB + binbuf 21MB + blkcnt 32KB = 98.4MB
    unsigned short* A  = (unsigned short*)d_ws;              // N*256 bf16 [aggr|h]
    unsigned short* pW = A + (size_t)N_NODES * 256;          // 3 * 32768 bf16
    int* cnt    = (int*)(pW + 3 * 32768);                    // N ints
    int* bkt    = cnt + N_NODES;                             // N*64 ints
    int2* binbuf = (int2*)(bkt + (size_t)N_NODES * CAP);     // 8*1024*320 int2
    int* blkcnt = (int*)(binbuf + (size_t)NPART * NBLK_A * SUBCAP);   // 1024*8 ints

    for (int i = 0; i < 3; ++i)
        pack_w<<<128, 256, 0, stream>>>(w_rel[i], w_root[i], pW + (size_t)i * 32768);
    convert_x<<<(N_NODES * 64 + 255) / 256, 256, 0, stream>>>(x, A);

    // ---- bucket CSR: radix partition + L2-local fill (reused by 3 layers) ----
    hipMemsetAsync(cnt, 0, N_NODES * sizeof(int), stream);
    partition_edges<<<NBLK_A, 256, 0, stream>>>(src, dst, binbuf, blkcnt);
    bucket_fill_binned<<<2048, 256, 0, stream>>>((const int*)binbuf, blkcnt, cnt, bkt);

    const int gblocks = (N_NODES * 64 + 255) / 256;
    const int xblocks = (N_NODES + 255) / 256;

    // Each layer: gather h-part -> aggr-part; transform -> h-part (in place)
    gather_bucket<<<gblocks, 256, 0, stream>>>(cnt, bkt, A);
    mfma_transform<false><<<xblocks, 256, 0, stream>>>(A, pW + 0 * 32768, b_rel[0],
                                                       nullptr, nullptr, nullptr);
    gather_bucket<<<gblocks, 256, 0, stream>>>(cnt, bkt, A);
    mfma_transform<false><<<xblocks, 256, 0, stream>>>(A, pW + 1 * 32768, b_rel[1],
                                                       nullptr, nullptr, nullptr);
    gather_bucket<<<gblocks, 256, 0, stream>>>(cnt, bkt, A);
    mfma_transform<true><<<xblocks, 256, 0, stream>>>(A, pW + 2 * 32768, b_rel[2],
                                                      w_out, b_out, (float*)d_out);
}

// Round 9
// 358.085 us; speedup vs baseline: 1.0240x; 1.0224x over previous
//
#include <hip/hip_runtime.h>

constexpr int N_NODES = 100000;
constexpr int N_EDGES = 1600000;
constexpr int CAP = 64;      // bucket capacity; degree ~Poisson(16), P(deg>=64)~1e-19
constexpr int NPB = 128;     // nodes per bin
constexpr int NBIN = (N_NODES + NPB - 1) / NPB;   // 782
constexpr int NGRP = 32;     // block groups in pass A
constexpr int SEGCAP = 128;  // per-(bin,group) pair capacity; mean 64, +8 sigma
constexpr int NBLK_A = 1024;
constexpr int EPB = (N_EDGES + NBLK_A - 1) / NBLK_A;   // 1563

typedef short short8 __attribute__((ext_vector_type(8)));
typedef float f32x4 __attribute__((ext_vector_type(4)));

__device__ __forceinline__ unsigned short f2bf(float f) {
    unsigned int u = __float_as_uint(f);
    unsigned int r = (u + 0x7fff + ((u >> 16) & 1)) >> 16;   // RTN-even
    return (unsigned short)r;
}
__device__ __forceinline__ float bflo(unsigned int u) { return __uint_as_float(u << 16); }
__device__ __forceinline__ float bfhi(unsigned int u) { return __uint_as_float(u & 0xffff0000u); }

// A-matrix row layout: [0..127] = aggr (k<128, W_rel), [128..255] = h (k>=128, W_root)

// ---------------- weight packing: B-fragment order, bf16 ----------------
__global__ __launch_bounds__(256) void pack_w(const float* __restrict__ wrel,
                                              const float* __restrict__ wroot,
                                              unsigned short* __restrict__ packed) {
    int t = blockIdx.x * 256 + threadIdx.x;   // 0..32767
    int j = t & 7, lane = (t >> 3) & 63, ks = (t >> 9) & 7, nt = (t >> 12) & 7;
    int k = ks * 32 + ((lane >> 4) << 3) + j;
    int n = nt * 16 + (lane & 15);
    float v = (k < 128) ? wrel[n * 128 + k] : wroot[n * 128 + (k - 128)];
    packed[t] = f2bf(v);
}

// x fp32 -> h-part bf16 of A
__global__ __launch_bounds__(256) void convert_x(const float* __restrict__ x,
                                                 unsigned short* __restrict__ A) {
    int i = blockIdx.x * 256 + threadIdx.x;
    if (i >= N_NODES * 64) return;
    int node = i >> 6, c2 = (i & 63) * 2;
    float2 v = *(const float2*)&x[(size_t)node * 128 + c2];
    unsigned int out = (unsigned int)f2bf(v.x) | ((unsigned int)f2bf(v.y) << 16);
    *(unsigned int*)&A[(size_t)node * 256 + 128 + c2] = out;
}

// ---------------- pass A: partition packed (dloc,s) pairs into bins ---------
// bin = dst>>7 (128 nodes/bin). Per-thread register edge buffer (unrolled,
// compile-time indexed), LDS histogram for in-block rank, ONE global
// atomicAdd per (bin, group-of-32-blocks) to reserve space in a static
// region. Pair packed to 4B: (d&127)<<17 | s  (s < 2^17).
__global__ __launch_bounds__(256) void partition_pairs(const int* __restrict__ src,
                                                       const int* __restrict__ dst,
                                                       int* __restrict__ gcnt,
                                                       int* __restrict__ pairs) {
    __shared__ int hist[NBIN];
    __shared__ int bl[NBIN];
    for (int j = threadIdx.x; j < NBIN; j += 256) hist[j] = 0;
    __syncthreads();
    int base = blockIdx.x * EPB;
    int grp = blockIdx.x >> 5;   // 0..31
    int pv[7], pr[7], pb[7];
    bool val[7];
    #pragma unroll
    for (int k = 0; k < 7; ++k) {
        int off = k * 256 + threadIdx.x;
        int e = base + off;
        val[k] = (off < EPB) && (e < N_EDGES);
        pv[k] = pr[k] = pb[k] = 0;
        if (val[k]) {
            int d = __builtin_nontemporal_load(dst + e);
            int s = __builtin_nontemporal_load(src + e);
            pb[k] = d >> 7;
            pv[k] = ((d & 127) << 17) | s;
            pr[k] = atomicAdd(&hist[pb[k]], 1);
        }
    }
    __syncthreads();
    for (int j = threadIdx.x; j < NBIN; j += 256) {
        int h = hist[j];
        bl[j] = h ? atomicAdd(&gcnt[j * NGRP + grp], h) : 0;
    }
    __syncthreads();
    #pragma unroll
    for (int k = 0; k < 7; ++k)
        if (val[k]) {
            int idx = bl[pb[k]] + pr[k];
            if (idx < SEGCAP)
                pairs[((size_t)pb[k] * NGRP + grp) * SEGCAP + idx] = pv[k];
        }
}

// ---------------- pass B: build whole bucket lines in LDS, write once ------
// Block j owns nodes [j*128, j*128+128). Buckets staged in 32KB LDS via LDS
// atomics, then cnt/bkt written as full coalesced lines. Zero global atomics.
__global__ __launch_bounds__(256) void bucket_build(const int* __restrict__ gcnt,
                                                    const int* __restrict__ pairs,
                                                    int* __restrict__ cnt,
                                                    int* __restrict__ bkt) {
    __shared__ int cnt_l[NPB];
    __shared__ int bkt_l[NPB * CAP];   // 32KB
    int j = blockIdx.x;
    for (int t = threadIdx.x; t < NPB; t += 256) cnt_l[t] = 0;
    __syncthreads();
    int wave = threadIdx.x >> 6, lane = threadIdx.x & 63;
    for (int g = wave; g < NGRP; g += 4) {
        int n = gcnt[j * NGRP + g];
        n = (n > SEGCAP) ? SEGCAP : n;
        const int* seg = pairs + ((size_t)j * NGRP + g) * SEGCAP;
        for (int k = lane; k < n; k += 64) {
            int p = __builtin_nontemporal_load(seg + k);
            int dl = p >> 17;
            int s = p & 0x1FFFF;
            int pos = atomicAdd(&cnt_l[dl], 1);
            if (pos < CAP) bkt_l[(dl << 6) + pos] = s;
        }
    }
    __syncthreads();
    int base_node = j * NPB;
    // bkt: NPB nodes x 16 uint4, fully coalesced
    for (int idx = threadIdx.x; idx < NPB * 16; idx += 256) {
        int node = base_node + (idx >> 4);
        if (node < N_NODES)
            ((uint4*)bkt)[(size_t)node * 16 + (idx & 15)] = ((const uint4*)bkt_l)[idx];
    }
    for (int t = threadIdx.x; t < NPB; t += 256) {
        int node = base_node + t;
        if (node < N_NODES) cnt[node] = cnt_l[t];
    }
}

// ---------------- per-layer kernels ----------------
// One 64-lane wave per node, in-place on A: reads h-part (offset 128) of
// neighbor rows, writes aggr-part (offset 0) of own row. lane>>4 = edge slot
// (4 rows in flight), lane&15 = 16B chunk; 2x unrolled -> 8 rows in flight.
__global__ __launch_bounds__(256) void gather_bucket(const int* __restrict__ cnt_arr,
                                                     const int* __restrict__ bkt,
                                                     unsigned short* __restrict__ A) {
    int wid = (blockIdx.x * 256 + threadIdx.x) >> 6;
    int lane = threadIdx.x & 63;
    if (wid >= N_NODES) return;
    int cnt = cnt_arr[wid];
    cnt = (cnt > CAP) ? CAP : cnt;
    const int* bp = bkt + (wid << 6);
    int g = lane >> 4;
    int ch = lane & 15;
    float acc[8] = {};
    int e = 0;
    for (; e + 8 <= cnt; e += 8) {
        int s0 = bp[e + g];
        int s1 = bp[e + 4 + g];
        uint4 u0 = *(const uint4*)&A[(size_t)s0 * 256 + 128 + ch * 8];
        uint4 u1 = *(const uint4*)&A[(size_t)s1 * 256 + 128 + ch * 8];
        acc[0] += bflo(u0.x); acc[1] += bfhi(u0.x);
        acc[2] += bflo(u0.y); acc[3] += bfhi(u0.y);
        acc[4] += bflo(u0.z); acc[5] += bfhi(u0.z);
        acc[6] += bflo(u0.w); acc[7] += bfhi(u0.w);
        acc[0] += bflo(u1.x); acc[1] += bfhi(u1.x);
        acc[2] += bflo(u1.y); acc[3] += bfhi(u1.y);
        acc[4] += bflo(u1.z); acc[5] += bfhi(u1.z);
        acc[6] += bflo(u1.w); acc[7] += bfhi(u1.w);
    }
    for (; e < cnt; e += 4) {
        int ei = e + g;
        if (ei < cnt) {
            int s0 = bp[ei];
            uint4 u0 = *(const uint4*)&A[(size_t)s0 * 256 + 128 + ch * 8];
            acc[0] += bflo(u0.x); acc[1] += bfhi(u0.x);
            acc[2] += bflo(u0.y); acc[3] += bfhi(u0.y);
            acc[4] += bflo(u0.z); acc[5] += bfhi(u0.z);
            acc[6] += bflo(u0.w); acc[7] += bfhi(u0.w);
        }
    }
    #pragma unroll
    for (int j = 0; j < 8; ++j) {
        acc[j] += __shfl_xor(acc[j], 16);
        acc[j] += __shfl_xor(acc[j], 32);
    }
    if (g == 0) {
        uint4 o;
        o.x = (unsigned int)f2bf(acc[0]) | ((unsigned int)f2bf(acc[1]) << 16);
        o.y = (unsigned int)f2bf(acc[2]) | ((unsigned int)f2bf(acc[3]) << 16);
        o.z = (unsigned int)f2bf(acc[4]) | ((unsigned int)f2bf(acc[5]) << 16);
        o.w = (unsigned int)f2bf(acc[6]) | ((unsigned int)f2bf(acc[7]) << 16);
        *(uint4*)&A[(size_t)wid * 256 + ch * 8] = o;
    }
}

// relu(A[N,256] x W[256,128] + b). Block = 4 waves, 256 rows. Weights staged
// in 64KB LDS (R6-measured best). LAST=false: write h' bf16 in-place into A's
// h-part. LAST=true: fuse output layer: out[row] = dot(relu_row, w_out)+b_out.
template <bool LAST>
__global__ __launch_bounds__(256) void mfma_transform(unsigned short* __restrict__ A,
                                                      const unsigned short* __restrict__ packedW,
                                                      const float* __restrict__ brel,
                                                      const float* __restrict__ w_out,
                                                      const float* __restrict__ b_out,
                                                      float* __restrict__ outF) {
    __shared__ unsigned short sW[32768];   // 64KB
    {
        const uint4* g = (const uint4*)packedW;
        uint4* s = (uint4*)sW;
        for (int i = threadIdx.x; i < 4096; i += 256) s[i] = g[i];
    }
    __syncthreads();
    int wave = threadIdx.x >> 6, lane = threadIdx.x & 63;
    int l15 = lane & 15, lhi = lane >> 4;
    int brow = blockIdx.x * 256 + wave * 64;
    float bias[8], wo[8];
    #pragma unroll
    for (int nt = 0; nt < 8; ++nt) {
        bias[nt] = brel[nt * 16 + l15];
        if (LAST) wo[nt] = w_out[nt * 16 + l15];
    }
    float bout = LAST ? b_out[0] : 0.f;

    for (int rtp = 0; rtp < 2; ++rtp) {
        int r0 = brow + rtp * 32;
        short8 a[2][8];
        #pragma unroll
        for (int rt = 0; rt < 2; ++rt) {
            int row = r0 + rt * 16 + l15;
            if (row >= N_NODES) row = N_NODES - 1;
            const unsigned short* ap = &A[(size_t)row * 256 + lhi * 8];
            #pragma unroll
            for (int ks = 0; ks < 8; ++ks) a[rt][ks] = *(const short8*)(ap + ks * 32);
        }
        f32x4 acc[2][8] = {};
        #pragma unroll
        for (int nt = 0; nt < 8; ++nt) {
            #pragma unroll
            for (int ks = 0; ks < 8; ++ks) {
                short8 b = *(const short8*)&sW[(size_t)((nt * 8 + ks) * 64 + lane) * 8];
                acc[0][nt] = __builtin_amdgcn_mfma_f32_16x16x32_bf16(a[0][ks], b, acc[0][nt], 0, 0, 0);
                acc[1][nt] = __builtin_amdgcn_mfma_f32_16x16x32_bf16(a[1][ks], b, acc[1][nt], 0, 0, 0);
            }
        }
        #pragma unroll
        for (int rt = 0; rt < 2; ++rt) {
            if (LAST) {
                #pragma unroll
                for (int rg = 0; rg < 4; ++rg) {
                    float p = 0.f;
                    #pragma unroll
                    for (int nt = 0; nt < 8; ++nt)
                        p += fmaxf(acc[rt][nt][rg] + bias[nt], 0.f) * wo[nt];
                    p += __shfl_xor(p, 1);
                    p += __shfl_xor(p, 2);
                    p += __shfl_xor(p, 4);
                    p += __shfl_xor(p, 8);
                    int row = r0 + rt * 16 + lhi * 4 + rg;
                    if (l15 == 0 && row < N_NODES) outF[row] = p + bout;
                }
            } else {
                #pragma unroll
                for (int nt = 0; nt < 8; ++nt) {
                    #pragma unroll
                    for (int rg = 0; rg < 4; ++rg) {
                        int row = r0 + rt * 16 + lhi * 4 + rg;
                        if (row < N_NODES) {
                            float v = fmaxf(acc[rt][nt][rg] + bias[nt], 0.f);
                            A[(size_t)row * 256 + 128 + nt * 16 + l15] = f2bf(v);
                        }
                    }
                }
            }
        }
    }
}

extern "C" void kernel_launch(void* const* d_in, const int* in_sizes, int n_in,
                              void* d_out, int out_size, void* d_ws, size_t ws_size,
                              hipStream_t stream) {
    const float* x      = (const float*)d_in[0];
    const int*   edge   = (const int*)d_in[1];
    const int*   src    = edge;
    const int*   dst    = edge + N_EDGES;
    const float* w_rel[3]  = {(const float*)d_in[2], (const float*)d_in[5], (const float*)d_in[8]};
    const float* b_rel[3]  = {(const float*)d_in[3], (const float*)d_in[6], (const float*)d_in[9]};
    const float* w_root[3] = {(const float*)d_in[4], (const float*)d_in[7], (const float*)d_in[10]};
    const float* w_out  = (const float*)d_in[11];
    const float* b_out  = (const float*)d_in[12];

    // ws: A 51.2MB + pW 0.2 + cnt 0.4 + bkt 25.6 + gcnt 0.1 + pairs 12.8 = 90.3MB
    unsigned short* A  = (unsigned short*)d_ws;              // N*256 bf16 [aggr|h]
    unsigned short* pW = A + (size_t)N_NODES * 256;          // 3 * 32768 bf16
    int* cnt   = (int*)(pW + 3 * 32768);                     // N ints
    int* bkt   = cnt + N_NODES;                              // N*64 ints
    int* gcnt  = bkt + (size_t)N_NODES * CAP;                // NBIN*NGRP ints
    int* pairs = gcnt + NBIN * NGRP;                         // NBIN*NGRP*SEGCAP ints

    for (int i = 0; i < 3; ++i)
        pack_w<<<128, 256, 0, stream>>>(w_rel[i], w_root[i], pW + (size_t)i * 32768);
    convert_x<<<(N_NODES * 64 + 255) / 256, 256, 0, stream>>>(x, A);

    // ---- bucket CSR: bin pairs, then build whole bucket lines in LDS ----
    hipMemsetAsync(gcnt, 0, NBIN * NGRP * sizeof(int), stream);
    partition_pairs<<<NBLK_A, 256, 0, stream>>>(src, dst, gcnt, pairs);
    bucket_build<<<NBIN, 256, 0, stream>>>(gcnt, pairs, cnt, bkt);

    const int gblocks = (N_NODES * 64 + 255) / 256;
    const int xblocks = (N_NODES + 255) / 256;

    // Each layer: gather h-part -> aggr-part; transform -> h-part (in place)
    gather_bucket<<<gblocks, 256, 0, stream>>>(cnt, bkt, A);
    mfma_transform<false><<<xblocks, 256, 0, stream>>>(A, pW + 0 * 32768, b_rel[0],
                                                       nullptr, nullptr, nullptr);
    gather_bucket<<<gblocks, 256, 0, stream>>>(cnt, bkt, A);
    mfma_transform<false><<<xblocks, 256, 0, stream>>>(A, pW + 1 * 32768, b_rel[1],
                                                       nullptr, nullptr, nullptr);
    gather_bucket<<<gblocks, 256, 0, stream>>>(cnt, bkt, A);
    mfma_transform<true><<<xblocks, 256, 0, stream>>>(A, pW + 2 * 32768, b_rel[2],
                                                      w_out, b_out, (float*)d_out);
}